// Round 6
// baseline (5176.728 us; speedup 1.0000x reference)
//
#include <hip/hip_runtime.h>

typedef float f32x4 __attribute__((ext_vector_type(4)));
typedef _Float16 f16x8 __attribute__((ext_vector_type(8)));
typedef unsigned int u32x4 __attribute__((ext_vector_type(4)));

__device__ __forceinline__ unsigned short f2h_u(float f){
  union { _Float16 h; unsigned short u; } cv; cv.h = (_Float16)f; return cv.u;
}
__device__ __forceinline__ float h2f(unsigned short u){
  union { unsigned short u; _Float16 h; } cv; cv.u = u; return (float)cv.h;
}
__device__ __forceinline__ float sigmoidf_(float x){ return 1.0f / (1.0f + __expf(-x)); }

// gemmz part slab indexing: slab w, row b (64), vec4 slot sp (16 slots)
#define GP(w,b,sp) ((((w)*64 + (b))<<6) + ((sp)<<2))

// ---------- conversion: x (B,S,I) f32 -> (S,B,I) f16 ----------
__global__ __launch_bounds__(256) void cvt_x(const float* __restrict__ in,
                                             unsigned short* __restrict__ out){
  int idx = blockIdx.x * 256 + threadIdx.x;
  int d4 = idx * 4;
  int s = d4 >> 16, b = (d4 >> 10) & 63, k = d4 & 1023;
  const float4 v = *(const float4*)(in + (size_t)b * 262144 + (size_t)s * 1024 + k);
  ushort4 o;
  o.x = f2h_u(v.x); o.y = f2h_u(v.y); o.z = f2h_u(v.z); o.w = f2h_u(v.w);
  *(ushort4*)(out + d4) = o;
}

struct P8 { const float* p[8]; };

// ---------- plain convert 8 (H,H) f32 mats -> [8][1024][1024] f16 ----------
__global__ __launch_bounds__(256) void cvt_w8(P8 mats, unsigned short* __restrict__ out){
  int idx = blockIdx.x * 256 + threadIdx.x;
  int e = idx * 4;
  int mi = e >> 20, off = e & 1048575;
  const float4 v = *(const float4*)(mats.p[mi] + off);
  ushort4 o;
  o.x = f2h_u(v.x); o.y = f2h_u(v.y); o.z = f2h_u(v.z); o.w = f2h_u(v.w);
  *(ushort4*)(out + e) = o;
}

// ---------- pack 8 (H,H) f32 mats interleaved: row j <- mats[j&7][j>>3][:] ----------
__global__ __launch_bounds__(256) void pack8(P8 mats, unsigned short* __restrict__ out){
  int idx = blockIdx.x * 256 + threadIdx.x;
  int e = idx * 4;
  int j = e >> 10, k = e & 1023;
  int m = j & 7, row = j >> 3;
  const float4 v = *(const float4*)(mats.p[m] + (size_t)row * 1024 + k);
  ushort4 o;
  o.x = f2h_u(v.x); o.y = f2h_u(v.y); o.z = f2h_u(v.z); o.w = f2h_u(v.w);
  *(ushort4*)(out + e) = o;
}

// ---------- fused masked-linear GEMM: z_g = (x@W^T) * sigmoid(x@Wm^T), f16 out ----------
__global__ __launch_bounds__(256, 2) void gemmz(
    const unsigned short* __restrict__ Xh,
    const unsigned short* __restrict__ Wg,
    unsigned short* __restrict__ Z01,
    unsigned short* __restrict__ Z23){
  const int tid = threadIdx.x, wave = tid >> 6, lane = tid & 63;
  const int r = lane & 15, q = lane >> 4;
  const int bid = blockIdx.x;
  const int m0 = (bid & 255) * 64;
  const int n0 = ((bid >> 8) & 15) * 64;
  const int g  = bid >> 12;
  extern __shared__ float part[];                // [4][64][64] f32 = 64 KiB

  const unsigned short* WL = Wg + ((size_t)(2 * g) << 20);
  const unsigned short* WM = WL + (1u << 20);

  f32x4 accL[4][4], accM[4][4];
#pragma unroll
  for (int a = 0; a < 4; ++a)
#pragma unroll
    for (int b = 0; b < 4; ++b){ accL[a][b] = 0.f; accM[a][b] = 0.f; }

  const int kb = wave * 256 + q * 8;
#pragma unroll
  for (int kk = 0; kk < 8; ++kk){
    const int k = kb + kk * 32;
    f16x8 xf[4], wl[4], wm[4];
#pragma unroll
    for (int mt = 0; mt < 4; ++mt)
      xf[mt] = *(const f16x8*)(Xh + (size_t)(m0 + mt * 16 + r) * 1024 + k);
#pragma unroll
    for (int nt = 0; nt < 4; ++nt){
      wl[nt] = *(const f16x8*)(WL + (size_t)(n0 + nt * 16 + r) * 1024 + k);
      wm[nt] = *(const f16x8*)(WM + (size_t)(n0 + nt * 16 + r) * 1024 + k);
    }
#pragma unroll
    for (int nt = 0; nt < 4; ++nt)
#pragma unroll
      for (int mt = 0; mt < 4; ++mt){
        accL[nt][mt] = __builtin_amdgcn_mfma_f32_16x16x32_f16(wl[nt], xf[mt], accL[nt][mt], 0, 0, 0);
        accM[nt][mt] = __builtin_amdgcn_mfma_f32_16x16x32_f16(wm[nt], xf[mt], accM[nt][mt], 0, 0, 0);
      }
  }

  const int ml = tid & 63, nc = tid >> 6;
  f32x4 yL[4], yM[4];
#pragma unroll
  for (int nt = 0; nt < 4; ++nt)
#pragma unroll
    for (int mt = 0; mt < 4; ++mt)
      *(f32x4*)&part[GP(wave, mt * 16 + r, ((4 * nt + q) ^ (2 * (r & 7))))] = accL[nt][mt];
  __syncthreads();
#pragma unroll
  for (int j = 0; j < 4; ++j){
    yL[j] = 0.f;
#pragma unroll
    for (int w = 0; w < 4; ++w)
      yL[j] += *(const f32x4*)&part[GP(w, ml, ((4 * nc + j) ^ (2 * (ml & 7))))];
  }
  __syncthreads();
#pragma unroll
  for (int nt = 0; nt < 4; ++nt)
#pragma unroll
    for (int mt = 0; mt < 4; ++mt)
      *(f32x4*)&part[GP(wave, mt * 16 + r, ((4 * nt + q) ^ (2 * (r & 7))))] = accM[nt][mt];
  __syncthreads();
#pragma unroll
  for (int j = 0; j < 4; ++j){
    yM[j] = 0.f;
#pragma unroll
    for (int w = 0; w < 4; ++w)
      yM[j] += *(const f32x4*)&part[GP(w, ml, ((4 * nc + j) ^ (2 * (ml & 7))))];
  }

  unsigned short* Zp = (g < 2) ? (Z01 + ((size_t)g << 24)) : (Z23 + ((size_t)(g - 2) << 24));
#pragma unroll
  for (int j = 0; j < 4; ++j){
    union { ushort4 u; uint2 d; } o;
    o.u.x = f2h_u(yL[j][0] * sigmoidf_(yM[j][0]));
    o.u.y = f2h_u(yL[j][1] * sigmoidf_(yM[j][1]));
    o.u.z = f2h_u(yL[j][2] * sigmoidf_(yM[j][2]));
    o.u.w = f2h_u(yL[j][3] * sigmoidf_(yM[j][3]));
    *(uint2*)(Zp + (size_t)(m0 + ml) * 1024 + n0 + nc * 16 + j * 4) = o.d;
  }
}

// ---------- persistent recurrence: 128 blocks x 512 thr ----------
// Block bi owns cols n0=bi*8 (64 packed U rows = 4 n-quarters of 16).
// Wave w: n-quarter nq=w>>1, K-half kh=w&1 (512). Partials: part[8][64][20-stride]
// (derived 2-way-max banks on both f32x4 writes and f32x4 combine reads).
__global__ __launch_bounds__(512, 1) void lstm_rec(
    const unsigned short* __restrict__ Z01,  // gate planes f,i (in d_out)
    const unsigned short* __restrict__ Z23,  // gate planes o,c (in ws)
    const unsigned short* __restrict__ Ug,   // packed [8192][1024] f16
    const float* __restrict__ bF, const float* __restrict__ bI,
    const float* __restrict__ bO, const float* __restrict__ bC,
    unsigned short* __restrict__ hh,         // [256][65536] f16 (write-once)
    unsigned int* __restrict__ flags,        // [128]
    float* __restrict__ out){
  const int tid = threadIdx.x, wave = tid >> 6, lane = tid & 63;
  const int bi = blockIdx.x, n0 = bi * 8, j0 = bi * 64;
  const int r = lane & 15, q = lane >> 4;
  const int nq = wave >> 1, kh = wave & 1;
  __shared__ float part[8 * 1284];           // 41,088 B (slab stride 1284, row stride 20)

  // weights: 16 rows (j0 + nq*16 + r), K-half kh — 64 VGPR resident
  f16x8 uf[16];
#pragma unroll
  for (int kk = 0; kk < 16; ++kk)
    uf[kk] = *(const f16x8*)(Ug + (size_t)(j0 + nq * 16 + r) * 1024 + kh * 512 + kk * 32 + q * 8);

  const int cb = tid >> 3, cl = tid & 7;     // combine: thread owns (batch cb, col cl)
  const float bFv = bF[n0 + cl], bIv = bI[n0 + cl], bOv = bO[n0 + cl], bCv = bC[n0 + cl];
  const int sA = (cl >> 1) * 2;              // slab pair for this col's n-quarter
  const int rdoff = cb * 20 + (cl & 1) * 8;
  float c_reg = 0.f;

#pragma unroll 1
  for (int s = 0; s < 256; ++s){
    // z loads early (read-only; hide under poll + h-load)
    size_t moff = (size_t)(s * 64 + cb) * 1024 + n0 + cl;
    unsigned short z0r = Z01[moff], z1r = Z01[16777216 + moff];
    unsigned short z2r = Z23[moff], z3r = Z23[16777216 + moff];

    f32x4 acc[4];
    acc[0] = 0.f; acc[1] = 0.f; acc[2] = 0.f; acc[3] = 0.f;

    if (s > 0){
      if (wave == 0){
        const u32x4* fl = (const u32x4*)flags;
        const unsigned tgt = (unsigned)s;
        for (;;){
          u32x4 v;
          asm volatile("global_load_dwordx4 %0, %1, off sc0 sc1\n\t"
                       "s_waitcnt vmcnt(0)"
                       : "=v"(v) : "v"(fl + (lane & 31)) : "memory");
          int ok = (v[0] >= tgt) & (v[1] >= tgt) & (v[2] >= tgt) & (v[3] >= tgt);
          if (__all(ok)) break;
        }
      }
      __syncthreads();

      const unsigned short* hb = hh + (size_t)(s - 1) * 65536;
#pragma unroll
      for (int c = 0; c < 4; ++c){
        f16x8 hf[4][4];
#pragma unroll
        for (int k2 = 0; k2 < 4; ++k2)
#pragma unroll
          for (int mt = 0; mt < 4; ++mt)
            hf[k2][mt] = *(const f16x8*)(hb + (size_t)(mt * 16 + r) * 1024 + kh * 512 + (c * 4 + k2) * 32 + q * 8);
        __builtin_amdgcn_s_setprio(1);
#pragma unroll
        for (int k2 = 0; k2 < 4; ++k2)
#pragma unroll
          for (int mt = 0; mt < 4; ++mt)
            acc[mt] = __builtin_amdgcn_mfma_f32_16x16x32_f16(uf[c * 4 + k2], hf[k2][mt], acc[mt], 0, 0, 0);
        __builtin_amdgcn_s_setprio(0);
      }
    }

    // partial write: lane (r,q) holds D rows q*4..+3 (n-local), col b=mt*16+r
#pragma unroll
    for (int mt = 0; mt < 4; ++mt)
      *(f32x4*)&part[wave * 1284 + (mt * 16 + r) * 20 + q * 4] = acc[mt];
    __syncthreads();

    // combine: y[m] = sum over 2 K-half slabs at [b=cb][n16=(cl&1)*8+m]
    f32x4 y0 = *(const f32x4*)&part[sA * 1284 + rdoff];
    f32x4 y1 = *(const f32x4*)&part[sA * 1284 + rdoff + 4];
    y0 += *(const f32x4*)&part[(sA + 1) * 1284 + rdoff];
    y1 += *(const f32x4*)&part[(sA + 1) * 1284 + rdoff + 4];

    float fg = sigmoidf_(h2f(z0r) + y0[0] * sigmoidf_(y0[1]) + bFv);
    float ig = sigmoidf_(h2f(z1r) + y0[2] * sigmoidf_(y0[3]) + bIv);
    float og = sigmoidf_(h2f(z2r) + y1[0] * sigmoidf_(y1[1]) + bOv);
    float cg = tanhf   (h2f(z3r) + y1[2] * sigmoidf_(y1[3]) + bCv);
    c_reg = cg * ig + fg * c_reg;
    float h = og * c_reg;

    // h store: pack 8 cols -> dwordx4, write-through LLC
    float h1 = __shfl_down(h, 1), h2v = __shfl_down(h, 2), h3 = __shfl_down(h, 3),
          h4 = __shfl_down(h, 4), h5 = __shfl_down(h, 5), h6 = __shfl_down(h, 6),
          h7 = __shfl_down(h, 7);
    if (cl == 0){
      u32x4 pv;
      pv[0] = (unsigned)f2h_u(h)   | ((unsigned)f2h_u(h1) << 16);
      pv[1] = (unsigned)f2h_u(h2v) | ((unsigned)f2h_u(h3) << 16);
      pv[2] = (unsigned)f2h_u(h4)  | ((unsigned)f2h_u(h5) << 16);
      pv[3] = (unsigned)f2h_u(h6)  | ((unsigned)f2h_u(h7) << 16);
      unsigned short* hw = hh + (size_t)s * 65536 + (size_t)cb * 1024 + n0;
      asm volatile("global_store_dwordx4 %0, %1, off sc0 sc1" :: "v"(hw), "v"(pv) : "memory");
    }
    if (s == 255){
      out[16777216 + cb * 1024 + n0 + cl] = h;
      out[16777216 + 65536 + cb * 1024 + n0 + cl] = c_reg;
      break;
    }
    asm volatile("s_waitcnt vmcnt(0)" ::: "memory");
    __syncthreads();
    if (tid == 0){
      unsigned int v = (unsigned)(s + 1);
      asm volatile("global_store_dword %0, %1, off sc0 sc1" :: "v"(flags + bi), "v"(v) : "memory");
    }
  }
}

// ---------- expand hh (S,B,H f16) -> out (B,S,H f32) ----------
__global__ __launch_bounds__(256) void expand_out(const unsigned short* __restrict__ hh,
                                                  float* __restrict__ out){
  int idx = blockIdx.x * 256 + threadIdx.x;
  int e = idx * 8;
  int s = e >> 16, b = (e >> 10) & 63, n = e & 1023;
  ushort4 a = *(const ushort4*)(hh + e);
  ushort4 c = *(const ushort4*)(hh + e + 4);
  size_t o = ((size_t)b * 256 + s) * 1024 + n;
  float4 f0 = { h2f(a.x), h2f(a.y), h2f(a.z), h2f(a.w) };
  float4 f1 = { h2f(c.x), h2f(c.y), h2f(c.z), h2f(c.w) };
  *(float4*)(out + o) = f0;
  *(float4*)(out + o + 4) = f1;
}

// ================= fallback (validated round-3 kernel, small ws) =================
__global__ __launch_bounds__(256, 1) void lstm_rec_fb(
    const unsigned short* __restrict__ Xh,
    const unsigned short* __restrict__ Up,
    const unsigned short* __restrict__ Wp,
    const float* __restrict__ bF, const float* __restrict__ bI,
    const float* __restrict__ bO, const float* __restrict__ bC,
    unsigned short* __restrict__ hhist,      // [257][65536]
    unsigned int* __restrict__ flags,        // [256]
    float* __restrict__ out){
  const int tid = threadIdx.x, wave = tid >> 6, lane = tid & 63;
  const int bi = blockIdx.x, n0 = bi * 4, j0 = bi * 32;
  const int r = lane & 15, q = lane >> 4;
  __shared__ __align__(16) float part[4][64][68];

  f16x8 uf[2][8], wf[2][8];
#pragma unroll
  for (int nt = 0; nt < 2; ++nt)
#pragma unroll
    for (int kk = 0; kk < 8; ++kk){
      size_t off = (size_t)(j0 + nt * 16 + r) * 1024 + wave * 256 + kk * 32 + q * 8;
      uf[nt][kk] = *(const f16x8*)(Up + off);
      wf[nt][kk] = *(const f16x8*)(Wp + off);
    }
  const int cb = tid >> 2, cl = tid & 3;
  const float bFv = bF[n0 + cl], bIv = bI[n0 + cl], bOv = bO[n0 + cl], bCv = bC[n0 + cl];
  float c_reg = 0.f;

#pragma unroll 1
  for (int s = 0; s < 256; ++s){
    const unsigned short* xs = Xh + (size_t)s * 65536;
    f32x4 ax[2][4];
#pragma unroll
    for (int nt = 0; nt < 2; ++nt)
#pragma unroll
      for (int mt = 0; mt < 4; ++mt) ax[nt][mt] = 0.f;
#pragma unroll
    for (int kk = 0; kk < 8; ++kk){
      const int k = wave * 256 + kk * 32 + q * 8;
      f16x8 xf[4];
#pragma unroll
      for (int mt = 0; mt < 4; ++mt)
        xf[mt] = *(const f16x8*)(xs + (size_t)(mt * 16 + r) * 1024 + k);
#pragma unroll
      for (int nt = 0; nt < 2; ++nt)
#pragma unroll
        for (int mt = 0; mt < 4; ++mt)
          ax[nt][mt] = __builtin_amdgcn_mfma_f32_16x16x32_f16(wf[nt][kk], xf[mt], ax[nt][mt], 0, 0, 0);
    }
    if (s > 0){
      if (wave == 0){
        const u32x4* fl = (const u32x4*)flags;
        const unsigned tgt = (unsigned)s;
        for (;;){
          u32x4 v;
          asm volatile("global_load_dwordx4 %0, %1, off sc0 sc1\n\t"
                       "s_waitcnt vmcnt(0)"
                       : "=v"(v) : "v"(fl + lane) : "memory");
          int ok = (v[0] >= tgt) & (v[1] >= tgt) & (v[2] >= tgt) & (v[3] >= tgt);
          if (__all(ok)) break;
        }
      }
      __syncthreads();
    }
    const unsigned short* hb = hhist + (size_t)s * 65536;
    f32x4 ah[2][4];
#pragma unroll
    for (int nt = 0; nt < 2; ++nt)
#pragma unroll
      for (int mt = 0; mt < 4; ++mt) ah[nt][mt] = 0.f;
#pragma unroll
    for (int kk = 0; kk < 8; ++kk){
      const int k = wave * 256 + kk * 32 + q * 8;
      f16x8 hf[4];
#pragma unroll
      for (int mt = 0; mt < 4; ++mt)
        hf[mt] = *(const f16x8*)(hb + (size_t)(mt * 16 + r) * 1024 + k);
#pragma unroll
      for (int nt = 0; nt < 2; ++nt)
#pragma unroll
        for (int mt = 0; mt < 4; ++mt)
          ah[nt][mt] = __builtin_amdgcn_mfma_f32_16x16x32_f16(uf[nt][kk], hf[mt], ah[nt][mt], 0, 0, 0);
    }
#pragma unroll
    for (int nt = 0; nt < 2; ++nt)
#pragma unroll
      for (int mt = 0; mt < 4; ++mt){
        *(f32x4*)&part[wave][mt * 16 + r][nt * 16 + q * 4]      = ah[nt][mt];
        *(f32x4*)&part[wave][mt * 16 + r][32 + nt * 16 + q * 4] = ax[nt][mt];
      }
    __syncthreads();
    f32x4 y0 = 0.f, y1 = 0.f, z0 = 0.f, z1 = 0.f;
#pragma unroll
    for (int w = 0; w < 4; ++w){
      y0 += *(const f32x4*)&part[w][cb][cl * 8];
      y1 += *(const f32x4*)&part[w][cb][cl * 8 + 4];
      z0 += *(const f32x4*)&part[w][cb][32 + cl * 8];
      z1 += *(const f32x4*)&part[w][cb][32 + cl * 8 + 4];
    }
    size_t grow = ((size_t)cb * 256 + s) * 1024 + n0 + cl;
    float fg = sigmoidf_(z0[0] * sigmoidf_(z0[1]) + y0[0] * sigmoidf_(y0[1]) + bFv);
    float ig = sigmoidf_(z0[2] * sigmoidf_(z0[3]) + y0[2] * sigmoidf_(y0[3]) + bIv);
    float og = sigmoidf_(z1[0] * sigmoidf_(z1[1]) + y1[0] * sigmoidf_(y1[1]) + bOv);
    float cg = tanhf   (z1[2] * sigmoidf_(z1[3]) + y1[2] * sigmoidf_(y1[3]) + bCv);
    c_reg = cg * ig + fg * c_reg;
    float h = og * c_reg;
    out[grow] = h;
    float hn = __shfl_xor(h, 1);
    if (!(cl & 1)){
      unsigned int pv = (unsigned)f2h_u(h) | ((unsigned)f2h_u(hn) << 16);
      const unsigned short* hw = hhist + (size_t)(s + 1) * 65536 + (size_t)cb * 1024 + n0 + cl;
      asm volatile("global_store_dword %0, %1, off sc0 sc1" :: "v"(hw), "v"(pv) : "memory");
    }
    if (s == 255){
      out[16777216 + cb * 1024 + n0 + cl] = h;
      out[16777216 + 65536 + cb * 1024 + n0 + cl] = c_reg;
      break;
    }
    asm volatile("s_waitcnt vmcnt(0)" ::: "memory");
    __syncthreads();
    if (tid == 0){
      unsigned int v = (unsigned)(s + 1);
      asm volatile("global_store_dword %0, %1, off sc0 sc1" :: "v"(flags + bi), "v"(v) : "memory");
    }
  }
}

// ---------- host launch ----------
extern "C" void kernel_launch(void* const* d_in, const int* in_sizes, int n_in,
                              void* d_out, int out_size, void* d_ws, size_t ws_size,
                              hipStream_t stream){
  (void)in_sizes; (void)n_in; (void)out_size;
  char* ws = (char*)d_ws;
  const float* bF = (const float*)d_in[17];
  const float* bI = (const float*)d_in[18];
  const float* bO = (const float*)d_in[19];
  const float* bC = (const float*)d_in[20];
  float* outp = (float*)d_out;
  P8 w8, u8;
  for (int m = 0; m < 8; ++m){
    w8.p[m] = (const float*)d_in[1 + m];
    u8.p[m] = (const float*)d_in[9 + m];
  }

  const size_t NEED_P = 167772672;   // xh 32M + wg 16M + ug 16M + z23 64M + hh 32M + flags

  if (ws_size >= NEED_P){
    unsigned short* xh  = (unsigned short*)(ws);               // 33,554,432 B
    unsigned short* wg  = (unsigned short*)(ws + 33554432);    // 16,777,216 B
    unsigned short* ug  = (unsigned short*)(ws + 50331648);    // 16,777,216 B
    unsigned short* z23 = (unsigned short*)(ws + 67108864);    // 67,108,864 B
    unsigned short* hh  = (unsigned short*)(ws + 134217728);   // 33,554,432 B
    unsigned int* flags = (unsigned int*)  (ws + 167772160);   //        512 B
    unsigned short* z01 = (unsigned short*)d_out;              // gate planes f,i (64 MB)

    (void)hipMemsetAsync(flags, 0, 512, stream);
    cvt_x<<<16384, 256, 0, stream>>>((const float*)d_in[0], xh);
    cvt_w8<<<8192, 256, 0, stream>>>(w8, wg);
    pack8<<<8192, 256, 0, stream>>>(u8, ug);
    gemmz<<<16384, 256, 65536, stream>>>(xh, wg, z01, z23);

    void* args[] = { (void*)&z01, (void*)&z23, (void*)&ug,
                     (void*)&bF, (void*)&bI, (void*)&bO, (void*)&bC,
                     (void*)&hh, (void*)&flags, (void*)&outp };
    hipError_t e = hipLaunchCooperativeKernel((const void*)lstm_rec, dim3(128), dim3(512),
                                              args, 0u, stream);
    if (e != hipSuccess)
      lstm_rec<<<128, 512, 0, stream>>>(z01, z23, ug, bF, bI, bO, bC, hh, flags, outp);
    expand_out<<<8192, 256, 0, stream>>>(hh, outp);
  } else {
    // fallback: validated round-3 path (~100.8 MB ws)
    unsigned short* xh    = (unsigned short*)(ws);               // 33,554,432 B
    unsigned short* up    = (unsigned short*)(ws + 33554432);    // 16,777,216 B
    unsigned short* wp    = (unsigned short*)(ws + 50331648);    // 16,777,216 B
    unsigned short* hhist = (unsigned short*)(ws + 67108864);    // 33,685,504 B
    unsigned int*   flags = (unsigned int*)  (ws + 100794368);   //      1,024 B

    (void)hipMemsetAsync(hhist, 0, 131072, stream);
    (void)hipMemsetAsync(flags, 0, 1024, stream);
    cvt_x<<<16384, 256, 0, stream>>>((const float*)d_in[0], xh);
    pack8<<<8192, 256, 0, stream>>>(w8, wp);
    pack8<<<8192, 256, 0, stream>>>(u8, up);

    void* args[] = { (void*)&xh, (void*)&up, (void*)&wp,
                     (void*)&bF, (void*)&bI, (void*)&bO, (void*)&bC,
                     (void*)&hhist, (void*)&flags, (void*)&outp };
    hipError_t e = hipLaunchCooperativeKernel((const void*)lstm_rec_fb, dim3(256), dim3(256),
                                              args, 0u, stream);
    if (e != hipSuccess)
      lstm_rec_fb<<<256, 256, 0, stream>>>(xh, up, wp, bF, bI, bO, bC, hhist, flags, outp);
  }
}

// Round 7
// 2817.820 us; speedup vs baseline: 1.8371x; 1.8371x over previous
//
#include <hip/hip_runtime.h>

typedef float f32x4 __attribute__((ext_vector_type(4)));
typedef _Float16 f16x8 __attribute__((ext_vector_type(8)));
typedef unsigned int u32x4 __attribute__((ext_vector_type(4)));

__device__ __forceinline__ unsigned short f2h_u(float f){
  union { _Float16 h; unsigned short u; } cv; cv.h = (_Float16)f; return cv.u;
}
__device__ __forceinline__ float h2f(unsigned short u){
  union { unsigned short u; _Float16 h; } cv; cv.u = u; return (float)cv.h;
}
__device__ __forceinline__ float sigmoidf_(float x){ return 1.0f / (1.0f + __expf(-x)); }

// gemmz part slab indexing: slab w, row b (64), vec4 slot sp (16 slots)
#define GP(w,b,sp) ((((w)*64 + (b))<<6) + ((sp)<<2))

// ---------- conversion: x (B,S,I) f32 -> (S,B,I) f16 ----------
__global__ __launch_bounds__(256) void cvt_x(const float* __restrict__ in,
                                             unsigned short* __restrict__ out){
  int idx = blockIdx.x * 256 + threadIdx.x;
  int d4 = idx * 4;
  int s = d4 >> 16, b = (d4 >> 10) & 63, k = d4 & 1023;
  const float4 v = *(const float4*)(in + (size_t)b * 262144 + (size_t)s * 1024 + k);
  ushort4 o;
  o.x = f2h_u(v.x); o.y = f2h_u(v.y); o.z = f2h_u(v.z); o.w = f2h_u(v.w);
  *(ushort4*)(out + d4) = o;
}

struct P8 { const float* p[8]; };

// ---------- plain convert 8 (H,H) f32 mats -> [8][1024][1024] f16 ----------
__global__ __launch_bounds__(256) void cvt_w8(P8 mats, unsigned short* __restrict__ out){
  int idx = blockIdx.x * 256 + threadIdx.x;
  int e = idx * 4;
  int mi = e >> 20, off = e & 1048575;
  const float4 v = *(const float4*)(mats.p[mi] + off);
  ushort4 o;
  o.x = f2h_u(v.x); o.y = f2h_u(v.y); o.z = f2h_u(v.z); o.w = f2h_u(v.w);
  *(ushort4*)(out + e) = o;
}

// ---------- pack 8 (H,H) f32 mats interleaved: row j <- mats[j&7][j>>3][:] ----------
__global__ __launch_bounds__(256) void pack8(P8 mats, unsigned short* __restrict__ out){
  int idx = blockIdx.x * 256 + threadIdx.x;
  int e = idx * 4;
  int j = e >> 10, k = e & 1023;
  int m = j & 7, row = j >> 3;
  const float4 v = *(const float4*)(mats.p[m] + (size_t)row * 1024 + k);
  ushort4 o;
  o.x = f2h_u(v.x); o.y = f2h_u(v.y); o.z = f2h_u(v.z); o.w = f2h_u(v.w);
  *(ushort4*)(out + e) = o;
}

// ---------- fused masked-linear GEMM: z_g = (x@W^T) * sigmoid(x@Wm^T) ----------
// Output TRANSPOSED planes: zT_g[col][m] (col 0..1023, m = s*64+b 0..16383), f16.
__global__ __launch_bounds__(256, 2) void gemmz(
    const unsigned short* __restrict__ Xh,
    const unsigned short* __restrict__ Wg,
    unsigned short* __restrict__ Z01,
    unsigned short* __restrict__ Z23){
  const int tid = threadIdx.x, wave = tid >> 6, lane = tid & 63;
  const int r = lane & 15, q = lane >> 4;
  const int bid = blockIdx.x;
  const int m0 = (bid & 255) * 64;
  const int n0 = ((bid >> 8) & 15) * 64;
  const int g  = bid >> 12;
  extern __shared__ float part[];                // [4][64][64] f32 = 64 KiB

  const unsigned short* WL = Wg + ((size_t)(2 * g) << 20);
  const unsigned short* WM = WL + (1u << 20);

  f32x4 accL[4][4], accM[4][4];
#pragma unroll
  for (int a = 0; a < 4; ++a)
#pragma unroll
    for (int b = 0; b < 4; ++b){ accL[a][b] = 0.f; accM[a][b] = 0.f; }

  const int kb = wave * 256 + q * 8;
#pragma unroll
  for (int kk = 0; kk < 8; ++kk){
    const int k = kb + kk * 32;
    f16x8 xf[4], wl[4], wm[4];
#pragma unroll
    for (int mt = 0; mt < 4; ++mt)
      xf[mt] = *(const f16x8*)(Xh + (size_t)(m0 + mt * 16 + r) * 1024 + k);
#pragma unroll
    for (int nt = 0; nt < 4; ++nt){
      wl[nt] = *(const f16x8*)(WL + (size_t)(n0 + nt * 16 + r) * 1024 + k);
      wm[nt] = *(const f16x8*)(WM + (size_t)(n0 + nt * 16 + r) * 1024 + k);
    }
#pragma unroll
    for (int nt = 0; nt < 4; ++nt)
#pragma unroll
      for (int mt = 0; mt < 4; ++mt){
        accL[nt][mt] = __builtin_amdgcn_mfma_f32_16x16x32_f16(wl[nt], xf[mt], accL[nt][mt], 0, 0, 0);
        accM[nt][mt] = __builtin_amdgcn_mfma_f32_16x16x32_f16(wm[nt], xf[mt], accM[nt][mt], 0, 0, 0);
      }
  }

  const int ml = tid & 63, nc = tid >> 6;
  f32x4 yL[4], yM[4];
#pragma unroll
  for (int nt = 0; nt < 4; ++nt)
#pragma unroll
    for (int mt = 0; mt < 4; ++mt)
      *(f32x4*)&part[GP(wave, mt * 16 + r, ((4 * nt + q) ^ (2 * (r & 7))))] = accL[nt][mt];
  __syncthreads();
#pragma unroll
  for (int j = 0; j < 4; ++j){
    yL[j] = 0.f;
#pragma unroll
    for (int w = 0; w < 4; ++w)
      yL[j] += *(const f32x4*)&part[GP(w, ml, ((4 * nc + j) ^ (2 * (ml & 7))))];
  }
  __syncthreads();
#pragma unroll
  for (int nt = 0; nt < 4; ++nt)
#pragma unroll
    for (int mt = 0; mt < 4; ++mt)
      *(f32x4*)&part[GP(wave, mt * 16 + r, ((4 * nt + q) ^ (2 * (r & 7))))] = accM[nt][mt];
  __syncthreads();
#pragma unroll
  for (int j = 0; j < 4; ++j){
    yM[j] = 0.f;
#pragma unroll
    for (int w = 0; w < 4; ++w)
      yM[j] += *(const f32x4*)&part[GP(w, ml, ((4 * nc + j) ^ (2 * (ml & 7))))];
  }

  unsigned short* Zp = (g < 2) ? (Z01 + ((size_t)g << 24)) : (Z23 + ((size_t)(g - 2) << 24));
#pragma unroll
  for (int j = 0; j < 4; ++j){
    const int colbase = n0 + nc * 16 + j * 4;
#pragma unroll
    for (int e = 0; e < 4; ++e){
      float v = yL[j][e] * sigmoidf_(yM[j][e]);
      Zp[(size_t)(colbase + e) * 16384 + m0 + ml] = f2h_u(v);   // lanes ml: coalesced 128B
    }
  }
}

// ---------- persistent recurrence: 256 blocks x 256 thr (round-3 shape) ----------
// Block bi owns cols n0=bi*4 (32 packed U rows). Wave w partitions K: [w*256,+256).
// x-side precomputed (zT planes). h loads: explicit double-buffered frag arrays
// (static indices) -> 8 b128 loads in flight under 16 MFMAs. h history write-once.
#define LOADC(dst, c)                                                               \
  _Pragma("unroll")                                                                 \
  for (int i = 0; i < 8; ++i)                                                       \
    dst[i] = *(const f16x8*)(hb + (size_t)((i >> 1) * 16 + r) * 1024 + (c) * 64 +   \
                             (i & 1) * 32 + q * 8);

#define COMPC(buf, c)                                                               \
  _Pragma("unroll")                                                                 \
  for (int kk = 0; kk < 2; ++kk)                                                    \
    _Pragma("unroll")                                                               \
    for (int nt = 0; nt < 2; ++nt)                                                  \
      _Pragma("unroll")                                                             \
      for (int mt = 0; mt < 4; ++mt)                                                \
        acc[nt][mt] = __builtin_amdgcn_mfma_f32_16x16x32_f16(                       \
            uf[nt][(c) * 2 + kk], buf[mt * 2 + kk], acc[nt][mt], 0, 0, 0);

__global__ __launch_bounds__(256, 1) void lstm_rec(
    const unsigned short* __restrict__ zF, const unsigned short* __restrict__ zI,
    const unsigned short* __restrict__ zO, const unsigned short* __restrict__ zC,
    const unsigned short* __restrict__ Ug,   // packed [8192][1024] f16
    const float* __restrict__ bF, const float* __restrict__ bI,
    const float* __restrict__ bO, const float* __restrict__ bC,
    unsigned short* __restrict__ hh,         // [256][65536] f16 (write-once slots)
    unsigned int* __restrict__ flags,        // [256]
    float* __restrict__ out){
  const int tid = threadIdx.x, wave = tid >> 6, lane = tid & 63;
  const int bi = blockIdx.x, n0 = bi * 4, j0 = bi * 32;
  const int r = lane & 15, q = lane >> 4;
  __shared__ __align__(16) float part[4][64][36];

  // resident weights: wave covers K slice [wave*256, +256): 16 frags = 64 VGPR
  f16x8 uf[2][8];
#pragma unroll
  for (int nt = 0; nt < 2; ++nt)
#pragma unroll
    for (int kk = 0; kk < 8; ++kk)
      uf[nt][kk] = *(const f16x8*)(Ug + (size_t)(j0 + nt * 16 + r) * 1024 + wave * 256 + kk * 32 + q * 8);

  const int cb = tid >> 2, cl = tid & 3;     // combine: thread owns (batch cb, col cl)
  const float bFv = bF[n0 + cl], bIv = bI[n0 + cl], bOv = bO[n0 + cl], bCv = bC[n0 + cl];
  const size_t zb = (size_t)(n0 + cl) * 16384 + cb;
  float c_reg = 0.f;

#pragma unroll 1
  for (int s = 0; s < 256; ++s){
    // z reads (line-efficient transposed planes; hide under poll)
    float zf = h2f(zF[zb + s * 64]);
    float zi = h2f(zI[zb + s * 64]);
    float zo = h2f(zO[zb + s * 64]);
    float zc = h2f(zC[zb + s * 64]);

    f32x4 acc[2][4];
#pragma unroll
    for (int nt = 0; nt < 2; ++nt)
#pragma unroll
      for (int mt = 0; mt < 4; ++mt) acc[nt][mt] = 0.f;

    if (s > 0){
      if (wave == 0){
        const u32x4* fl = (const u32x4*)flags;
        const unsigned tgt = (unsigned)s;
        for (;;){
          u32x4 v;
          asm volatile("global_load_dwordx4 %0, %1, off sc0 sc1\n\t"
                       "s_waitcnt vmcnt(0)"
                       : "=v"(v) : "v"(fl + lane) : "memory");
          int ok = (v[0] >= tgt) & (v[1] >= tgt) & (v[2] >= tgt) & (v[3] >= tgt);
          if (__all(ok)) break;
        }
      }
      __syncthreads();

      // h phase: 4 chunks of 64 K, double-buffered frag arrays (8 loads in flight)
      const unsigned short* hb = hh + (size_t)(s - 1) * 65536 + wave * 256;
      f16x8 hA[8], hB[8];
      LOADC(hA, 0);
      LOADC(hB, 1);
      COMPC(hA, 0);
      LOADC(hA, 2);
      COMPC(hB, 1);
      LOADC(hB, 3);
      COMPC(hA, 2);
      COMPC(hB, 3);
    }

    // cross-wave reduce: D[row=nl=nt*16+q*4+rg][col=b=mt*16+r] -> part[w][b][nl]
#pragma unroll
    for (int nt = 0; nt < 2; ++nt)
#pragma unroll
      for (int mt = 0; mt < 4; ++mt)
        *(f32x4*)&part[wave][mt * 16 + r][nt * 16 + q * 4] = acc[nt][mt];
    __syncthreads();

    f32x4 y0 = 0.f, y1 = 0.f;
#pragma unroll
    for (int w = 0; w < 4; ++w){
      y0 += *(const f32x4*)&part[w][cb][cl * 8];
      y1 += *(const f32x4*)&part[w][cb][cl * 8 + 4];
    }

    float fg = sigmoidf_(zf + y0[0] * sigmoidf_(y0[1]) + bFv);
    float ig = sigmoidf_(zi + y0[2] * sigmoidf_(y0[3]) + bIv);
    float og = sigmoidf_(zo + y1[0] * sigmoidf_(y1[1]) + bOv);
    float cg = tanhf   (zc + y1[2] * sigmoidf_(y1[3]) + bCv);
    c_reg = cg * ig + fg * c_reg;
    float h = og * c_reg;

    // h store: pack f16 pair, write-through to LLC (validated round-3 pattern)
    float hn = __shfl_xor(h, 1);
    if (!(cl & 1)){
      unsigned int pv = (unsigned)f2h_u(h) | ((unsigned)f2h_u(hn) << 16);
      const unsigned short* hw = hh + (size_t)s * 65536 + (size_t)cb * 1024 + n0 + cl;
      asm volatile("global_store_dword %0, %1, off sc0 sc1" :: "v"(hw), "v"(pv) : "memory");
    }
    if (s == 255){
      out[16777216 + cb * 1024 + n0 + cl] = h;
      out[16777216 + 65536 + cb * 1024 + n0 + cl] = c_reg;
      break;
    }
    asm volatile("s_waitcnt vmcnt(0)" ::: "memory");
    __syncthreads();
    if (tid == 0){
      unsigned int v = (unsigned)(s + 1);
      asm volatile("global_store_dword %0, %1, off sc0 sc1" :: "v"(flags + bi), "v"(v) : "memory");
    }
  }
}

// ---------- expand hh (S,B,H f16) -> out (B,S,H f32) ----------
__global__ __launch_bounds__(256) void expand_out(const unsigned short* __restrict__ hh,
                                                  float* __restrict__ out){
  int idx = blockIdx.x * 256 + threadIdx.x;
  int e = idx * 8;
  int s = e >> 16, b = (e >> 10) & 63, n = e & 1023;
  ushort4 a = *(const ushort4*)(hh + e);
  ushort4 c = *(const ushort4*)(hh + e + 4);
  size_t o = ((size_t)b * 256 + s) * 1024 + n;
  float4 f0 = { h2f(a.x), h2f(a.y), h2f(a.z), h2f(a.w) };
  float4 f1 = { h2f(c.x), h2f(c.y), h2f(c.z), h2f(c.w) };
  *(float4*)(out + o) = f0;
  *(float4*)(out + o + 4) = f1;
}

// ---------- host launch ----------
extern "C" void kernel_launch(void* const* d_in, const int* in_sizes, int n_in,
                              void* d_out, int out_size, void* d_ws, size_t ws_size,
                              hipStream_t stream){
  (void)in_sizes; (void)n_in; (void)out_size; (void)ws_size;
  char* ws = (char*)d_ws;
  const float* bF = (const float*)d_in[17];
  const float* bI = (const float*)d_in[18];
  const float* bO = (const float*)d_in[19];
  const float* bC = (const float*)d_in[20];
  float* outp = (float*)d_out;
  P8 w8, u8;
  for (int m = 0; m < 8; ++m){
    w8.p[m] = (const float*)d_in[1 + m];
    u8.p[m] = (const float*)d_in[9 + m];
  }

  unsigned short* xh  = (unsigned short*)(ws);               // 33,554,432 B
  unsigned short* wg  = (unsigned short*)(ws + 33554432);    // 16,777,216 B
  unsigned short* ug  = (unsigned short*)(ws + 50331648);    // 16,777,216 B
  unsigned short* z23 = (unsigned short*)(ws + 67108864);    // 67,108,864 B (zT_o, zT_c)
  unsigned short* hh  = (unsigned short*)(ws + 134217728);   // 33,554,432 B
  unsigned int* flags = (unsigned int*)  (ws + 167772160);   //      1,024 B
  unsigned short* z01 = (unsigned short*)d_out;              // zT_f, zT_i (64 MB)

  (void)hipMemsetAsync(flags, 0, 1024, stream);
  cvt_x<<<16384, 256, 0, stream>>>((const float*)d_in[0], xh);
  cvt_w8<<<8192, 256, 0, stream>>>(w8, wg);
  pack8<<<8192, 256, 0, stream>>>(u8, ug);
  gemmz<<<16384, 256, 65536, stream>>>(xh, wg, z01, z23);

  const unsigned short* zF = z01;
  const unsigned short* zI = z01 + 16777216;
  const unsigned short* zO = z23;
  const unsigned short* zC = z23 + 16777216;

  void* args[] = { (void*)&zF, (void*)&zI, (void*)&zO, (void*)&zC, (void*)&ug,
                   (void*)&bF, (void*)&bI, (void*)&bO, (void*)&bC,
                   (void*)&hh, (void*)&flags, (void*)&outp };
  hipError_t e = hipLaunchCooperativeKernel((const void*)lstm_rec, dim3(256), dim3(256),
                                            args, 0u, stream);
  if (e != hipSuccess)
    lstm_rec<<<256, 256, 0, stream>>>(zF, zI, zO, zC, ug, bF, bI, bO, bC, hh, flags, outp);

  expand_out<<<8192, 256, 0, stream>>>(hh, outp);
}